// Round 5
// baseline (886.717 us; speedup 1.0000x reference)
//
#include <hip/hip_runtime.h>
#include <hip/hip_bf16.h>
#include <stdint.h>

typedef __bf16 bf16x8 __attribute__((ext_vector_type(8)));
typedef __bf16 bf16x4 __attribute__((ext_vector_type(4)));
typedef float  f32x4  __attribute__((ext_vector_type(4)));

typedef __attribute__((address_space(3))) unsigned int as3_uint;
typedef const __attribute__((address_space(1))) unsigned int as1_uint;

#define NEGC (-1e9f)

__device__ __forceinline__ void async16(void* ldsPtr, const void* gPtr) {
    __builtin_amdgcn_global_load_lds((as1_uint*)(uintptr_t)gPtr,
                                     (as3_uint*)(uintptr_t)ldsPtr, 16, 0, 0);
}

// ---------------- LayerNorm: f32 in -> bf16 out ----------------
__global__ __launch_bounds__(256) void ln_kernel(const float* __restrict__ x,
                                                 const float* __restrict__ gw,
                                                 const float* __restrict__ bw,
                                                 __bf16* __restrict__ xn) {
    __shared__ float red[8];
    size_t row = blockIdx.x;
    int t = threadIdx.x;
    const float4* xr = (const float4*)(x + row * 1024);
    float4 v = xr[t];
    float s  = v.x + v.y + v.z + v.w;
    float ss = v.x*v.x + v.y*v.y + v.z*v.z + v.w*v.w;
    #pragma unroll
    for (int o = 32; o; o >>= 1) { s += __shfl_xor(s, o); ss += __shfl_xor(ss, o); }
    int wave = t >> 6, lane = t & 63;
    if (lane == 0) { red[wave*2] = s; red[wave*2+1] = ss; }
    __syncthreads();
    float S  = red[0] + red[2] + red[4] + red[6];
    float SS = red[1] + red[3] + red[5] + red[7];
    float mu  = S * (1.0f/1024.0f);
    float var = SS * (1.0f/1024.0f) - mu*mu;
    float rs  = rsqrtf(var + 1e-5f);
    float4 gv = ((const float4*)gw)[t];
    float4 bv = ((const float4*)bw)[t];
    bf16x4 o4;
    o4[0] = (__bf16)((v.x-mu)*rs*gv.x + bv.x);
    o4[1] = (__bf16)((v.y-mu)*rs*gv.y + bv.y);
    o4[2] = (__bf16)((v.z-mu)*rs*gv.z + bv.z);
    o4[3] = (__bf16)((v.w-mu)*rs*gv.w + bv.w);
    ((bf16x4*)(xn + row*1024))[t] = o4;
}

// ---------------- PHM weight builder: W^T (nn*kout rows x nn*kin cols) bf16 ----------------
__global__ __launch_bounds__(256) void phm_build(const float* __restrict__ A,
                                                 const float* __restrict__ S,
                                                 __bf16* __restrict__ Wt,
                                                 int nn, int kin, int kout) {
    __shared__ float sh[4][32][65];
    __shared__ float shA[64];
    int t  = threadIdx.x;
    int l0 = blockIdx.x * 64;
    int k0 = blockIdx.y * 32;
    int kt = nn * kin;  // 1024
    if (t < nn*nn*nn) shA[t] = A[t];
    for (int n = 0; n < nn; ++n) {
        #pragma unroll
        for (int i = 0; i < 8; ++i) {
            int e = t + i*256;
            int kk = e >> 6, ll = e & 63;
            sh[n][kk][ll] = S[((size_t)(n*kin) + k0 + kk)*kout + l0 + ll];
        }
    }
    __syncthreads();
    for (int a = 0; a < nn; ++a)
        for (int b = 0; b < nn; ++b) {
            #pragma unroll
            for (int i = 0; i < 8; ++i) {
                int e = t + i*256;
                int kk = e & 31, ll = e >> 5;
                float val = 0.f;
                for (int n = 0; n < nn; ++n)
                    val += shA[(n*nn + a)*nn + b] * sh[n][kk][ll];
                Wt[(size_t)(b*kout + l0 + ll)*kt + a*kin + k0 + kk] = (__bf16)val;
            }
        }
}

// ---------------- gate weight (1024 x 16) f32 ----------------
__global__ __launch_bounds__(256) void gatew_kernel(const float* __restrict__ A,
                                                    const float* __restrict__ S,
                                                    float* __restrict__ W) {
    int idx = blockIdx.x*256 + threadIdx.x;      // 16384 total
    int r = idx >> 4, c = idx & 15;
    int a = r >> 8, k = r & 255, b = c >> 2, l = c & 3;
    float v = 0.f;
    #pragma unroll
    for (int n = 0; n < 4; ++n)
        v += A[(n*4 + a)*4 + b] * S[((size_t)(n*256 + k))*4 + l];
    W[idx] = v;
}

// ---------------- 256x256 bf16 MFMA GEMM, burst-prefetch double-buffer ----
// 512 thr / 8 waves (2m x 4n), BK=64, LDS 128KiB double-buffered.
// LDS-read-minimal register schedule: per K-tile each wave loads its
// fragments ONCE (16 A + 8 B ds_read_b128, held in afr[4][2]/bfr[4][2]),
// vs the quadrant-re-read scheme's 48 (LDS BW was the measured pole:
// MfmaUtil pinned at 31% across 3 sync structures).
// Burst STAGE of next K-tile + vmcnt(8): waits target loads issued a full
// K-tile (~64 MFMA) earlier. 2 barriers per K-tile.
// Grid: 16 m-tiles x NTN n-tiles; block->tile map pairs the 2 m-tiles of an
// XCD on the same n-panel for back-to-back B reuse. Requires M==4096.
// BF16OUT==1: store bf16 at the FRONT of each f32 output row slot.
template<int BF16OUT>
__global__ __launch_bounds__(512, 2) void gemm256(const __bf16* __restrict__ A,
                                                  const __bf16* __restrict__ Bt,
                                                  const float* __restrict__ bias,
                                                  void* __restrict__ Cv,
                                                  int N, int K) {
    __shared__ __align__(16) char smem[131072];
    int tid = threadIdx.x;
    int wid = tid >> 6, lane = tid & 63;
    int l = blockIdx.x >> 3, xcd = blockIdx.x & 7;
    int mt = xcd * 2 + (l & 1), nt = l >> 1;
    int m0 = mt << 8, n0 = nt << 8;
    int wm = wid >> 2, wn = wid & 3;
    int lrow = lane & 15, lk = lane >> 4;

    f32x4 acc[8][4] = {};
    bf16x8 afr[4][2], bfr[4][2];

    auto STAGE = [&](int b, int u, int kt) {
        const __bf16* base = (u < 2) ? A : Bt;
        int row0 = (u < 2) ? m0 : n0;
        char* ldsu = smem + ((u < 2) ? 0 : 65536) + b * 32768 + ((u & 1) << 14);
        #pragma unroll
        for (int q = 0; q < 2; ++q) {
            int o = q * 8192 + tid * 16;
            int r = o >> 7;
            int src = ((o >> 4) & 7) ^ (r & 7);
            int row = ((u & 1) << 7) + r;
            async16(ldsu + q * 8192 + wid * 1024,
                    (const char*)base + (((size_t)(row0 + row)) * K + kt * 64 + src * 8) * 2);
        }
    };
    auto LDA = [&](int b, int mh) {          // 8 reads: 4 m-frags x 2 kk
        const char* Ab = smem + b * 32768;
        #pragma unroll
        for (int mf = 0; mf < 4; ++mf) {
            int ra = wm * 128 + (mh * 4 + mf) * 16 + lrow;
            #pragma unroll
            for (int kk = 0; kk < 2; ++kk)
                afr[mf][kk] = *(const bf16x8*)(Ab + ra * 128 + ((kk * 64 + lk * 16) ^ ((ra & 7) << 4)));
        }
    };
    auto LDB = [&](int b) {                  // 8 reads: 4 n-frags x 2 kk (whole strip)
        const char* Bb = smem + 65536 + b * 32768;
        #pragma unroll
        for (int nf = 0; nf < 4; ++nf) {
            int rb = wn * 64 + nf * 16 + lrow;
            #pragma unroll
            for (int kk = 0; kk < 2; ++kk)
                bfr[nf][kk] = *(const bf16x8*)(Bb + rb * 128 + ((kk * 64 + lk * 16) ^ ((rb & 7) << 4)));
        }
    };
    auto MMH = [&](int mh) {                 // 32 MFMA: one m-half over full n-strip
        __builtin_amdgcn_s_setprio(1);
        #pragma unroll
        for (int kk = 0; kk < 2; ++kk)
            #pragma unroll
            for (int mf = 0; mf < 4; ++mf)
                #pragma unroll
                for (int nf = 0; nf < 4; ++nf)
                    acc[mh*4+mf][nf] = __builtin_amdgcn_mfma_f32_16x16x32_bf16(
                        afr[mf][kk], bfr[nf][kk], acc[mh*4+mf][nf], 0, 0, 0);
        __builtin_amdgcn_s_setprio(0);
    };

    // prologue: K-tile 0 -> buf0 (8 loads/thread)
    STAGE(0,0,0); STAGE(0,1,0); STAGE(0,2,0); STAGE(0,3,0);

    int NT = K >> 6;                    // K-tiles of 64
    for (int i = 0; i < NT; ++i) {
        int b = i & 1;
        if (i + 1 < NT) {
            STAGE(b^1,0,i+1); STAGE(b^1,1,i+1); STAGE(b^1,2,i+1); STAGE(b^1,3,i+1);
            asm volatile("s_waitcnt vmcnt(8)" ::: "memory");   // buf b's loads done
        } else {
            asm volatile("s_waitcnt vmcnt(0)" ::: "memory");
        }
        __builtin_amdgcn_s_barrier();
        __builtin_amdgcn_sched_barrier(0);
        LDA(b,0); LDB(b);
        MMH(0);
        LDA(b,1);
        MMH(1);
        __builtin_amdgcn_s_barrier();                          // buf b reads all issued
    }

    // epilogue: C/D layout col=lane&15, row=(lane>>4)*4+reg
    #pragma unroll
    for (int nf = 0; nf < 4; ++nf) {
        int col = n0 + wn*64 + nf*16 + lrow;
        float bv = bias ? bias[col] : 0.f;
        #pragma unroll
        for (int mf = 0; mf < 8; ++mf) {
            int rowg = m0 + wm*128 + mf*16 + lk*4;
            #pragma unroll
            for (int r = 0; r < 4; ++r) {
                float val = acc[mf][nf][r] + bv;
                if (BF16OUT) {
                    ((__bf16*)((char*)Cv + (size_t)(rowg + r) * N * 4))[col] = (__bf16)val;
                } else {
                    ((float*)Cv)[(size_t)(rowg + r) * N + col] = val;
                }
            }
        }
    }
}

// ---------------- gate: logits + softmax probs Gp (4096 x 16) ----------------
__global__ __launch_bounds__(256) void gate_kernel(const __bf16* __restrict__ xn,
                                                   const float* __restrict__ Wg,
                                                   const float* __restrict__ gb,
                                                   float* __restrict__ Gp) {
    __shared__ float xr[16][65];
    __shared__ float red[16][17];
    size_t row = blockIdx.x;
    int t = threadIdx.x;
    bf16x4 v = ((const bf16x4*)(xn + row*1024))[t];
    #pragma unroll
    for (int q = 0; q < 4; ++q) {
        int e = t*4 + q;
        xr[e >> 6][e & 63] = (float)v[q];
    }
    __syncthreads();
    int h = t & 15, sl = t >> 4;
    float p = 0.f;
    #pragma unroll
    for (int u = 0; u < 64; ++u) p += xr[sl][u] * Wg[(sl*64 + u)*16 + h];
    red[sl][h] = p;
    __syncthreads();
    if (t < 16) {
        float logit = gb[t];
        #pragma unroll
        for (int s2 = 0; s2 < 16; ++s2) logit += red[s2][t];
        float m = logit;
        #pragma unroll
        for (int o = 8; o; o >>= 1) m = fmaxf(m, __shfl_xor(m, o, 16));
        float e = __expf(logit - m);
        float ssum = e;
        #pragma unroll
        for (int o = 8; o; o >>= 1) ssum += __shfl_xor(ssum, o, 16);
        Gp[row*16 + t] = e / ssum;
    }
}

// ---------------- scores + masked log-softmax + head-logsumexp -> transition ----------------
__global__ __launch_bounds__(512) void scores_kernel(const float* __restrict__ qk,
                                                     const float* __restrict__ Gp,
                                                     const int* __restrict__ lens,
                                                     float* __restrict__ out) {
    __shared__ float qs[8][1024];
    __shared__ float gps[8][16];
    __shared__ float wredA[8][8];
    __shared__ float wredB[8][8];
    int b  = blockIdx.y;
    int i0 = blockIdx.x * 8;
    int t  = threadIdx.x;
    int wave = t >> 6, lane = t & 63;
    int len = lens[b];
    const float4* qbase = (const float4*)(qk + ((size_t)b*512 + i0)*2048);
    #pragma unroll
    for (int s = 0; s < 4; ++s) {
        int e = t + s*512;
        int ti = e >> 8, c4 = e & 255;
        ((float4*)qs)[e] = qbase[ti*512 + c4];
    }
    if (t < 128) {
        int ti = t >> 4, h = t & 15;
        gps[ti][h] = Gp[((size_t)b*512 + i0 + ti)*16 + h];
    }
    __syncthreads();
    int j = t;
    const float4* kp = (const float4*)(qk + ((size_t)b*512 + j)*2048 + 1024);
    float acc[8], mace[8];
    #pragma unroll
    for (int ti = 0; ti < 8; ++ti) { acc[ti] = 0.f; mace[ti] = 0.f; }
    for (int h = 0; h < 16; ++h) {
        float4 kv[16];
        #pragma unroll
        for (int u = 0; u < 16; ++u) kv[u] = kp[h*16 + u];
        float sc[8];
        #pragma unroll
        for (int ti = 0; ti < 8; ++ti) {
            const float* qrow = &qs[ti][h*64];
            float d = 0.f;
            #pragma unroll
            for (int u = 0; u < 16; ++u)
                d += kv[u].x*qrow[u*4+0] + kv[u].y*qrow[u*4+1]
                   + kv[u].z*qrow[u*4+2] + kv[u].w*qrow[u*4+3];
            int i = i0 + ti;
            sc[ti] = (j > i && j < len) ? d * 0.125f : NEGC;
        }
        float mx[8];
        #pragma unroll
        for (int ti = 0; ti < 8; ++ti) {
            float vv = sc[ti];
            #pragma unroll
            for (int o = 32; o; o >>= 1) vv = fmaxf(vv, __shfl_xor(vv, o));
            mx[ti] = vv;
        }
        if (lane == 0) {
            #pragma unroll
            for (int ti = 0; ti < 8; ++ti) wredA[wave][ti] = mx[ti];
        }
        __syncthreads();
        float gmax[8], pex[8], sums[8];
        #pragma unroll
        for (int ti = 0; ti < 8; ++ti) {
            float m2 = wredA[0][ti];
            #pragma unroll
            for (int w = 1; w < 8; ++w) m2 = fmaxf(m2, wredA[w][ti]);
            gmax[ti] = m2;
            float pe = __expf(sc[ti] - m2);   // exp(NEG-...) underflows to 0 for invalid j
            pex[ti] = pe;
            float vv = pe;
            #pragma unroll
            for (int o = 32; o; o >>= 1) vv += __shfl_xor(vv, o);
            sums[ti] = vv;
        }
        if (lane == 0) {
            #pragma unroll
            for (int ti = 0; ti < 8; ++ti) wredB[wave][ti] = sums[ti];
        }
        __syncthreads();
        #pragma unroll
        for (int ti = 0; ti < 8; ++ti) {
            float gs = 0.f;
            #pragma unroll
            for (int w = 0; w < 8; ++w) gs += wredB[w][ti];
            float g = gps[ti][h];
            acc[ti]  += (pex[ti] / gs) * g;
            mace[ti] += g * __expf(-(gmax[ti] + __logf(gs)));
        }
    }
    #pragma unroll
    for (int ti = 0; ti < 8; ++ti) {
        int i = i0 + ti;
        float val;
        if (i >= len - 1)            val = NEGC;                     // dead row: exactly NEG
        else if (j > i && j < len)   val = __logf(acc[ti]);          // valid successor
        else                         val = NEGC + __logf(mace[ti]);  // masked position
        out[((size_t)b*512 + i)*512 + j] = val;
    }
}

// ---------------- vocab: bf16 logits (front of own f32 row slot) ->
//                   in-place f32 log-softmax, row staged in LDS ----------------
__global__ __launch_bounds__(256) void vocab_softmax_bf16(float* __restrict__ out) {
    __shared__ __align__(16) __bf16 srow[32000];
    __shared__ float red[8];
    size_t row = blockIdx.x;
    char* rowbase = (char*)out + row * (size_t)32000 * 4;
    const bf16x8* g8 = (const bf16x8*)rowbase;
    bf16x8* s8 = (bf16x8*)srow;
    int t = threadIdx.x, wave = t >> 6, lane = t & 63;
    float mx = -1e30f;
    for (int v = t; v < 4000; v += 256) {
        bf16x8 c = g8[v];
        s8[v] = c;
        #pragma unroll
        for (int jj = 0; jj < 8; ++jj) mx = fmaxf(mx, (float)c[jj]);
    }
    #pragma unroll
    for (int o = 32; o; o >>= 1) mx = fmaxf(mx, __shfl_xor(mx, o));
    if (lane == 0) red[wave] = mx;
    __syncthreads();
    mx = fmaxf(fmaxf(red[0], red[1]), fmaxf(red[2], red[3]));
    float sum = 0.f;
    for (int v = t; v < 4000; v += 256) {
        bf16x8 c = s8[v];
        #pragma unroll
        for (int jj = 0; jj < 8; ++jj) sum += __expf((float)c[jj] - mx);
    }
    #pragma unroll
    for (int o = 32; o; o >>= 1) sum += __shfl_xor(sum, o);
    if (lane == 0) red[4 + wave] = sum;
    __syncthreads();
    float lse = mx + __logf(red[4] + red[5] + red[6] + red[7]);
    float4* o4 = (float4*)rowbase;
    for (int v = t; v < 4000; v += 256) {
        bf16x8 c = s8[v];
        float4 a, b;
        a.x = (float)c[0] - lse; a.y = (float)c[1] - lse;
        a.z = (float)c[2] - lse; a.w = (float)c[3] - lse;
        b.x = (float)c[4] - lse; b.y = (float)c[5] - lse;
        b.z = (float)c[6] - lse; b.w = (float)c[7] - lse;
        o4[v*2]   = a;
        o4[v*2+1] = b;
    }
}

extern "C" void kernel_launch(void* const* d_in, const int* in_sizes, int n_in,
                              void* d_out, int out_size, void* d_ws, size_t ws_size,
                              hipStream_t stream) {
    (void)in_sizes; (void)n_in; (void)out_size; (void)ws_size;
    const float* x      = (const float*)d_in[0];
    const int*   lens   = (const int*)  d_in[1];
    const float* ln_g   = (const float*)d_in[2];
    const float* ln_b   = (const float*)d_in[3];
    const float* attn_A = (const float*)d_in[4];
    const float* attn_S = (const float*)d_in[5];
    const float* attn_b = (const float*)d_in[6];
    const float* gate_A = (const float*)d_in[7];
    const float* gate_S = (const float*)d_in[8];
    const float* gate_b = (const float*)d_in[9];
    const float* lm_A   = (const float*)d_in[10];
    const float* lm_S   = (const float*)d_in[11];
    const float* lm_b   = (const float*)d_in[12];

    float* out_trans = (float*)d_out;
    float* out_vocab = out_trans + (size_t)8*512*512;

    char* ws = (char*)d_ws;
    __bf16* xn     = (__bf16*)(ws);                 //  8,388,608 B
    __bf16* WtAttn = (__bf16*)(ws + 8388608);       //  4,194,304 B
    __bf16* WtLm   = (__bf16*)(ws + 12582912);      // 65,536,000 B
    float*  Wg     = (float*) (ws + 78118912);      //     65,536 B
    float*  qkbuf  = (float*) (ws + 78184448);      // 33,554,432 B
    float*  Gp     = (float*) (ws + 111738880);     //    262,144 B  (total ~112 MB)

    hipLaunchKernelGGL(ln_kernel,    dim3(4096),     dim3(256), 0, stream, x, ln_g, ln_b, xn);
    hipLaunchKernelGGL(gatew_kernel, dim3(64),       dim3(256), 0, stream, gate_A, gate_S, Wg);
    hipLaunchKernelGGL(phm_build,    dim3(8, 8),     dim3(256), 0, stream, attn_A, attn_S, WtAttn, 4, 256, 512);
    hipLaunchKernelGGL(phm_build,    dim3(250, 16),  dim3(256), 0, stream, lm_A, lm_S, WtLm, 2, 512, 16000);
    hipLaunchKernelGGL((gemm256<0>), dim3(128),      dim3(512), 0, stream,
                       xn, WtAttn, attn_b, (void*)qkbuf, 2048, 1024);
    hipLaunchKernelGGL(gate_kernel,  dim3(4096),     dim3(256), 0, stream, xn, Wg, gate_b, Gp);
    hipLaunchKernelGGL(scores_kernel,dim3(64, 8),    dim3(512), 0, stream, qkbuf, Gp, lens, out_trans);
    hipLaunchKernelGGL((gemm256<1>), dim3(2000),     dim3(512), 0, stream,
                       xn, WtLm, lm_b, (void*)out_vocab, 32000, 1024);
    hipLaunchKernelGGL(vocab_softmax_bf16, dim3(4096), dim3(256), 0, stream, out_vocab);
}

// Round 6
// 868.544 us; speedup vs baseline: 1.0209x; 1.0209x over previous
//
#include <hip/hip_runtime.h>
#include <hip/hip_bf16.h>
#include <stdint.h>

typedef __bf16 bf16x8 __attribute__((ext_vector_type(8)));
typedef __bf16 bf16x4 __attribute__((ext_vector_type(4)));
typedef float  f32x4  __attribute__((ext_vector_type(4)));

typedef __attribute__((address_space(3))) unsigned int as3_uint;
typedef const __attribute__((address_space(1))) unsigned int as1_uint;

#define NEGC (-1e9f)

__device__ __forceinline__ void async16(void* ldsPtr, const void* gPtr) {
    __builtin_amdgcn_global_load_lds((as1_uint*)(uintptr_t)gPtr,
                                     (as3_uint*)(uintptr_t)ldsPtr, 16, 0, 0);
}

// ---------------- LayerNorm: f32 in -> bf16 out ----------------
__global__ __launch_bounds__(256) void ln_kernel(const float* __restrict__ x,
                                                 const float* __restrict__ gw,
                                                 const float* __restrict__ bw,
                                                 __bf16* __restrict__ xn) {
    __shared__ float red[8];
    size_t row = blockIdx.x;
    int t = threadIdx.x;
    const float4* xr = (const float4*)(x + row * 1024);
    float4 v = xr[t];
    float s  = v.x + v.y + v.z + v.w;
    float ss = v.x*v.x + v.y*v.y + v.z*v.z + v.w*v.w;
    #pragma unroll
    for (int o = 32; o; o >>= 1) { s += __shfl_xor(s, o); ss += __shfl_xor(ss, o); }
    int wave = t >> 6, lane = t & 63;
    if (lane == 0) { red[wave*2] = s; red[wave*2+1] = ss; }
    __syncthreads();
    float S  = red[0] + red[2] + red[4] + red[6];
    float SS = red[1] + red[3] + red[5] + red[7];
    float mu  = S * (1.0f/1024.0f);
    float var = SS * (1.0f/1024.0f) - mu*mu;
    float rs  = rsqrtf(var + 1e-5f);
    float4 gv = ((const float4*)gw)[t];
    float4 bv = ((const float4*)bw)[t];
    bf16x4 o4;
    o4[0] = (__bf16)((v.x-mu)*rs*gv.x + bv.x);
    o4[1] = (__bf16)((v.y-mu)*rs*gv.y + bv.y);
    o4[2] = (__bf16)((v.z-mu)*rs*gv.z + bv.z);
    o4[3] = (__bf16)((v.w-mu)*rs*gv.w + bv.w);
    ((bf16x4*)(xn + row*1024))[t] = o4;
}

// ---------------- PHM weight builder: W^T (nn*kout rows x nn*kin cols) bf16 ----------------
__global__ __launch_bounds__(256) void phm_build(const float* __restrict__ A,
                                                 const float* __restrict__ S,
                                                 __bf16* __restrict__ Wt,
                                                 int nn, int kin, int kout) {
    __shared__ float sh[4][32][65];
    __shared__ float shA[64];
    int t  = threadIdx.x;
    int l0 = blockIdx.x * 64;
    int k0 = blockIdx.y * 32;
    int kt = nn * kin;  // 1024
    if (t < nn*nn*nn) shA[t] = A[t];
    for (int n = 0; n < nn; ++n) {
        #pragma unroll
        for (int i = 0; i < 8; ++i) {
            int e = t + i*256;
            int kk = e >> 6, ll = e & 63;
            sh[n][kk][ll] = S[((size_t)(n*kin) + k0 + kk)*kout + l0 + ll];
        }
    }
    __syncthreads();
    for (int a = 0; a < nn; ++a)
        for (int b = 0; b < nn; ++b) {
            #pragma unroll
            for (int i = 0; i < 8; ++i) {
                int e = t + i*256;
                int kk = e & 31, ll = e >> 5;
                float val = 0.f;
                for (int n = 0; n < nn; ++n)
                    val += shA[(n*nn + a)*nn + b] * sh[n][kk][ll];
                Wt[(size_t)(b*kout + l0 + ll)*kt + a*kin + k0 + kk] = (__bf16)val;
            }
        }
}

// ---------------- gate weight (1024 x 16) f32 ----------------
__global__ __launch_bounds__(256) void gatew_kernel(const float* __restrict__ A,
                                                    const float* __restrict__ S,
                                                    float* __restrict__ W) {
    int idx = blockIdx.x*256 + threadIdx.x;      // 16384 total
    int r = idx >> 4, c = idx & 15;
    int a = r >> 8, k = r & 255, b = c >> 2, l = c & 3;
    float v = 0.f;
    #pragma unroll
    for (int n = 0; n < 4; ++n)
        v += A[(n*4 + a)*4 + b] * S[((size_t)(n*256 + k))*4 + l];
    W[idx] = v;
}

// ---------------- 256x256 bf16 MFMA GEMM, 4-phase read-ahead pipeline ----
// 512 thr / 8 waves (2m x 4n), BK=64, LDS 128KiB double-buffered.
// Key fix vs prior rounds (MfmaUtil pinned 31-32%): phase-lockstep made LDS
// reads and MFMA run serially. Now each phase's ds_reads are issued one phase
// EARLY, so the LDS unit services them while the matrix pipe runs:
//   P1: MFMA(a_lo,b_lo)  reads b_lo (own, 4)
//   P2: MFMA(a_lo,b_hi)  reads b_hi (4) + pre-reads a_hi (8)
//   P3: MFMA(a_hi,b_hi)  no reads
//   P4: MFMA(a_hi,b_lo)  pre-reads next tile's a_lo (8) from other buffer
// Staging: 4 quadrant-matched units/K-tile (U1=A-mlo,U2=B-nlo,U3=B-nhi,
// U4=A-mhi), one per phase, counted vmcnt(2) (P4: vmcnt(4)). Cross-wave
// certification: every unit is landed + barrier-certified >=1 phase (A, L2)
// or >=2 phases (B, HBM) before any wave reads it.
// Grid: 16 m-tiles x NTN n-tiles; block->tile map pairs the 2 m-tiles of an
// XCD on the same n-panel for back-to-back B reuse. Requires M==4096.
// BF16OUT==1: store bf16 at the FRONT of each f32 output row slot.
template<int BF16OUT>
__global__ __launch_bounds__(512, 2) void gemm256(const __bf16* __restrict__ A,
                                                  const __bf16* __restrict__ Bt,
                                                  const float* __restrict__ bias,
                                                  void* __restrict__ Cv,
                                                  int N, int K) {
    __shared__ __align__(16) char smem[131072];
    int tid = threadIdx.x;
    int wid = tid >> 6, lane = tid & 63;
    int l = blockIdx.x >> 3, xcd = blockIdx.x & 7;
    int mt = xcd * 2 + (l & 1), nt = l >> 1;
    int m0 = mt << 8, n0 = nt << 8;
    int wm = wid >> 2, wn = wid & 3;
    int lrow = lane & 15, lk = lane >> 4;

    f32x4 acc[8][4] = {};
    bf16x8 afr_lo[4][2], afr_hi[4][2], bfr_lo[2][2], bfr_hi[2][2];

    // unit 0: A rows {0-63,128-191} (all waves' m-lo quadrant rows)
    // unit 3: A rows {64-127,192-255} (m-hi)
    // unit 1: B rows {0-31,64-95,128-159,192-223} (all waves' n-lo rows)
    // unit 2: B n-hi (n-lo + 32)
    auto STAGE = [&](int bsel, int unit, int kt) {
        bool isA = (unit == 0) || (unit == 3);
        int hi   = (unit == 2) || (unit == 3);
        const __bf16* base = isA ? A : Bt;
        int row0 = isA ? m0 : n0;
        char* mbase = smem + (isA ? 0 : 65536) + bsel * 32768;
        #pragma unroll
        for (int q = 0; q < 2; ++q) {
            int o  = tid * 16;
            int rl = o >> 7;                 // 0..63
            int grow, dstoff;
            if (isA) {
                grow   = q*128 + hi*64 + rl;
                dstoff = q*16384 + hi*8192 + wid*1024;
            } else {
                grow   = q*128 + (rl >> 5)*64 + hi*32 + (rl & 31);
                dstoff = q*16384 + (wid >> 2)*8192 + hi*4096 + (wid & 3)*1024;
            }
            int s = ((o >> 4) & 7) ^ (grow & 7);
            async16(mbase + dstoff,
                    (const char*)base + (((size_t)(row0 + grow))*K + kt*64 + s*8)*2);
        }
    };
    auto LDA = [&](bf16x8 (&dst)[4][2], int bsel, int mh) {     // 8 ds_read_b128
        const char* Ab = smem + bsel * 32768;
        #pragma unroll
        for (int mf = 0; mf < 4; ++mf) {
            int ra = wm*128 + (mh*4 + mf)*16 + lrow;
            #pragma unroll
            for (int kk = 0; kk < 2; ++kk)
                dst[mf][kk] = *(const bf16x8*)(Ab + ra*128 + ((kk*64 + lk*16) ^ ((ra & 7) << 4)));
        }
    };
    auto LDB = [&](bf16x8 (&dst)[2][2], int bsel, int nh) {     // 4 ds_read_b128
        const char* Bb = smem + 65536 + bsel * 32768;
        #pragma unroll
        for (int nf = 0; nf < 2; ++nf) {
            int rb = wn*64 + (nh*2 + nf)*16 + lrow;
            #pragma unroll
            for (int kk = 0; kk < 2; ++kk)
                dst[nf][kk] = *(const bf16x8*)(Bb + rb*128 + ((kk*64 + lk*16) ^ ((rb & 7) << 4)));
        }
    };
    auto MMQ = [&](bf16x8 (&a)[4][2], bf16x8 (&b)[2][2], int mh, int nh) {
        __builtin_amdgcn_s_setprio(1);
        #pragma unroll
        for (int kk = 0; kk < 2; ++kk)
            #pragma unroll
            for (int mf = 0; mf < 4; ++mf)
                #pragma unroll
                for (int nf = 0; nf < 2; ++nf)
                    acc[mh*4+mf][nh*2+nf] = __builtin_amdgcn_mfma_f32_16x16x32_bf16(
                        a[mf][kk], b[nf][kk], acc[mh*4+mf][nh*2+nf], 0, 0, 0);
        __builtin_amdgcn_s_setprio(0);
    };

    // prologue: K-tile 0 -> buf0, drain, pre-read a_lo
    STAGE(0,0,0); STAGE(0,1,0); STAGE(0,2,0); STAGE(0,3,0);
    asm volatile("s_waitcnt vmcnt(0)" ::: "memory");
    __builtin_amdgcn_s_barrier();
    LDA(afr_lo, 0, 0);

    int NT = K >> 6;
    for (int t = 0; t < NT; ++t) {
        int bs = t & 1, bn = bs ^ 1;
        bool pf = (t + 1 < NT);
        // P1
        if (pf) { STAGE(bn,0,t+1); asm volatile("s_waitcnt vmcnt(2)" ::: "memory"); }
        else    {                  asm volatile("s_waitcnt vmcnt(0)" ::: "memory"); }
        LDB(bfr_lo, bs, 0);
        __builtin_amdgcn_sched_barrier(0);
        MMQ(afr_lo, bfr_lo, 0, 0);
        __builtin_amdgcn_s_barrier();
        // P2
        if (pf) { STAGE(bn,1,t+1); asm volatile("s_waitcnt vmcnt(2)" ::: "memory"); }
        LDB(bfr_hi, bs, 1);
        LDA(afr_hi, bs, 1);
        __builtin_amdgcn_sched_barrier(0);
        MMQ(afr_lo, bfr_hi, 0, 1);
        __builtin_amdgcn_s_barrier();
        // P3
        if (pf) { STAGE(bn,2,t+1); asm volatile("s_waitcnt vmcnt(2)" ::: "memory"); }
        __builtin_amdgcn_sched_barrier(0);
        MMQ(afr_hi, bfr_hi, 1, 1);
        __builtin_amdgcn_s_barrier();
        // P4
        if (pf) { STAGE(bn,3,t+1); asm volatile("s_waitcnt vmcnt(4)" ::: "memory");
                  LDA(afr_lo, bn, 0); }
        __builtin_amdgcn_sched_barrier(0);
        MMQ(afr_hi, bfr_lo, 1, 0);
        __builtin_amdgcn_s_barrier();
    }

    // epilogue: C/D layout col=lane&15, row=(lane>>4)*4+reg
    #pragma unroll
    for (int nf = 0; nf < 4; ++nf) {
        int col = n0 + wn*64 + nf*16 + lrow;
        float bv = bias ? bias[col] : 0.f;
        #pragma unroll
        for (int mf = 0; mf < 8; ++mf) {
            int rowg = m0 + wm*128 + mf*16 + lk*4;
            #pragma unroll
            for (int r = 0; r < 4; ++r) {
                float val = acc[mf][nf][r] + bv;
                if (BF16OUT) {
                    ((__bf16*)((char*)Cv + (size_t)(rowg + r) * N * 4))[col] = (__bf16)val;
                } else {
                    ((float*)Cv)[(size_t)(rowg + r) * N + col] = val;
                }
            }
        }
    }
}

// ---------------- gate: logits + softmax probs Gp (4096 x 16) ----------------
__global__ __launch_bounds__(256) void gate_kernel(const __bf16* __restrict__ xn,
                                                   const float* __restrict__ Wg,
                                                   const float* __restrict__ gb,
                                                   float* __restrict__ Gp) {
    __shared__ float xr[16][65];
    __shared__ float red[16][17];
    size_t row = blockIdx.x;
    int t = threadIdx.x;
    bf16x4 v = ((const bf16x4*)(xn + row*1024))[t];
    #pragma unroll
    for (int q = 0; q < 4; ++q) {
        int e = t*4 + q;
        xr[e >> 6][e & 63] = (float)v[q];
    }
    __syncthreads();
    int h = t & 15, sl = t >> 4;
    float p = 0.f;
    #pragma unroll
    for (int u = 0; u < 64; ++u) p += xr[sl][u] * Wg[(sl*64 + u)*16 + h];
    red[sl][h] = p;
    __syncthreads();
    if (t < 16) {
        float logit = gb[t];
        #pragma unroll
        for (int s2 = 0; s2 < 16; ++s2) logit += red[s2][t];
        float m = logit;
        #pragma unroll
        for (int o = 8; o; o >>= 1) m = fmaxf(m, __shfl_xor(m, o, 16));
        float e = __expf(logit - m);
        float ssum = e;
        #pragma unroll
        for (int o = 8; o; o >>= 1) ssum += __shfl_xor(ssum, o, 16);
        Gp[row*16 + t] = e / ssum;
    }
}

// ---------------- scores + masked log-softmax + head-logsumexp -> transition ----------------
__global__ __launch_bounds__(512) void scores_kernel(const float* __restrict__ qk,
                                                     const float* __restrict__ Gp,
                                                     const int* __restrict__ lens,
                                                     float* __restrict__ out) {
    __shared__ float qs[8][1024];
    __shared__ float gps[8][16];
    __shared__ float wredA[8][8];
    __shared__ float wredB[8][8];
    int b  = blockIdx.y;
    int i0 = blockIdx.x * 8;
    int t  = threadIdx.x;
    int wave = t >> 6, lane = t & 63;
    int len = lens[b];
    const float4* qbase = (const float4*)(qk + ((size_t)b*512 + i0)*2048);
    #pragma unroll
    for (int s = 0; s < 4; ++s) {
        int e = t + s*512;
        int ti = e >> 8, c4 = e & 255;
        ((float4*)qs)[e] = qbase[ti*512 + c4];
    }
    if (t < 128) {
        int ti = t >> 4, h = t & 15;
        gps[ti][h] = Gp[((size_t)b*512 + i0 + ti)*16 + h];
    }
    __syncthreads();
    int j = t;
    const float4* kp = (const float4*)(qk + ((size_t)b*512 + j)*2048 + 1024);
    float acc[8], mace[8];
    #pragma unroll
    for (int ti = 0; ti < 8; ++ti) { acc[ti] = 0.f; mace[ti] = 0.f; }
    for (int h = 0; h < 16; ++h) {
        float4 kv[16];
        #pragma unroll
        for (int u = 0; u < 16; ++u) kv[u] = kp[h*16 + u];
        float sc[8];
        #pragma unroll
        for (int ti = 0; ti < 8; ++ti) {
            const float* qrow = &qs[ti][h*64];
            float d = 0.f;
            #pragma unroll
            for (int u = 0; u < 16; ++u)
                d += kv[u].x*qrow[u*4+0] + kv[u].y*qrow[u*4+1]
                   + kv[u].z*qrow[u*4+2] + kv[u].w*qrow[u*4+3];
            int i = i0 + ti;
            sc[ti] = (j > i && j < len) ? d * 0.125f : NEGC;
        }
        float mx[8];
        #pragma unroll
        for (int ti = 0; ti < 8; ++ti) {
            float vv = sc[ti];
            #pragma unroll
            for (int o = 32; o; o >>= 1) vv = fmaxf(vv, __shfl_xor(vv, o));
            mx[ti] = vv;
        }
        if (lane == 0) {
            #pragma unroll
            for (int ti = 0; ti < 8; ++ti) wredA[wave][ti] = mx[ti];
        }
        __syncthreads();
        float gmax[8], pex[8], sums[8];
        #pragma unroll
        for (int ti = 0; ti < 8; ++ti) {
            float m2 = wredA[0][ti];
            #pragma unroll
            for (int w = 1; w < 8; ++w) m2 = fmaxf(m2, wredA[w][ti]);
            gmax[ti] = m2;
            float pe = __expf(sc[ti] - m2);   // exp(NEG-...) underflows to 0 for invalid j
            pex[ti] = pe;
            float vv = pe;
            #pragma unroll
            for (int o = 32; o; o >>= 1) vv += __shfl_xor(vv, o);
            sums[ti] = vv;
        }
        if (lane == 0) {
            #pragma unroll
            for (int ti = 0; ti < 8; ++ti) wredB[wave][ti] = sums[ti];
        }
        __syncthreads();
        #pragma unroll
        for (int ti = 0; ti < 8; ++ti) {
            float gs = 0.f;
            #pragma unroll
            for (int w = 0; w < 8; ++w) gs += wredB[w][ti];
            float g = gps[ti][h];
            acc[ti]  += (pex[ti] / gs) * g;
            mace[ti] += g * __expf(-(gmax[ti] + __logf(gs)));
        }
    }
    #pragma unroll
    for (int ti = 0; ti < 8; ++ti) {
        int i = i0 + ti;
        float val;
        if (i >= len - 1)            val = NEGC;                     // dead row: exactly NEG
        else if (j > i && j < len)   val = __logf(acc[ti]);          // valid successor
        else                         val = NEGC + __logf(mace[ti]);  // masked position
        out[((size_t)b*512 + i)*512 + j] = val;
    }
}

// ---------------- vocab: bf16 logits (front of own f32 row slot) ->
//                   in-place f32 log-softmax, row staged in LDS ----------------
__global__ __launch_bounds__(256) void vocab_softmax_bf16(float* __restrict__ out) {
    __shared__ __align__(16) __bf16 srow[32000];
    __shared__ float red[8];
    size_t row = blockIdx.x;
    char* rowbase = (char*)out + row * (size_t)32000 * 4;
    const bf16x8* g8 = (const bf16x8*)rowbase;
    bf16x8* s8 = (bf16x8*)srow;
    int t = threadIdx.x, wave = t >> 6, lane = t & 63;
    float mx = -1e30f;
    for (int v = t; v < 4000; v += 256) {
        bf16x8 c = g8[v];
        s8[v] = c;
        #pragma unroll
        for (int jj = 0; jj < 8; ++jj) mx = fmaxf(mx, (float)c[jj]);
    }
    #pragma unroll
    for (int o = 32; o; o >>= 1) mx = fmaxf(mx, __shfl_xor(mx, o));
    if (lane == 0) red[wave] = mx;
    __syncthreads();
    mx = fmaxf(fmaxf(red[0], red[1]), fmaxf(red[2], red[3]));
    float sum = 0.f;
    for (int v = t; v < 4000; v += 256) {
        bf16x8 c = s8[v];
        #pragma unroll
        for (int jj = 0; jj < 8; ++jj) sum += __expf((float)c[jj] - mx);
    }
    #pragma unroll
    for (int o = 32; o; o >>= 1) sum += __shfl_xor(sum, o);
    if (lane == 0) red[4 + wave] = sum;
    __syncthreads();
    float lse = mx + __logf(red[4] + red[5] + red[6] + red[7]);
    float4* o4 = (float4*)rowbase;
    for (int v = t; v < 4000; v += 256) {
        bf16x8 c = s8[v];
        float4 a, b;
        a.x = (float)c[0] - lse; a.y = (float)c[1] - lse;
        a.z = (float)c[2] - lse; a.w = (float)c[3] - lse;
        b.x = (float)c[4] - lse; b.y = (float)c[5] - lse;
        b.z = (float)c[6] - lse; b.w = (float)c[7] - lse;
        o4[v*2]   = a;
        o4[v*2+1] = b;
    }
}

extern "C" void kernel_launch(void* const* d_in, const int* in_sizes, int n_in,
                              void* d_out, int out_size, void* d_ws, size_t ws_size,
                              hipStream_t stream) {
    (void)in_sizes; (void)n_in; (void)out_size; (void)ws_size;
    const float* x      = (const float*)d_in[0];
    const int*   lens   = (const int*)  d_in[1];
    const float* ln_g   = (const float*)d_in[2];
    const float* ln_b   = (const float*)d_in[3];
    const float* attn_A = (const float*)d_in[4];
    const float* attn_S = (const float*)d_in[5];
    const float* attn_b = (const float*)d_in[6];
    const float* gate_A = (const float*)d_in[7];
    const float* gate_S = (const float*)d_in[8];
    const float* gate_b = (const float*)d_in[9];
    const float* lm_A   = (const float*)d_in[10];
    const float* lm_S   = (const float*)d_in[11];
    const float* lm_b   = (const float*)d_in[12];

    float* out_trans = (float*)d_out;
    float* out_vocab = out_trans + (size_t)8*512*512;

    char* ws = (char*)d_ws;
    __bf16* xn     = (__bf16*)(ws);                 //  8,388,608 B
    __bf16* WtAttn = (__bf16*)(ws + 8388608);       //  4,194,304 B
    __bf16* WtLm   = (__bf16*)(ws + 12582912);      // 65,536,000 B
    float*  Wg     = (float*) (ws + 78118912);      //     65,536 B
    float*  qkbuf  = (float*) (ws + 78184448);      // 33,554,432 B
    float*  Gp     = (float*) (ws + 111738880);     //    262,144 B  (total ~112 MB)

    hipLaunchKernelGGL(ln_kernel,    dim3(4096),     dim3(256), 0, stream, x, ln_g, ln_b, xn);
    hipLaunchKernelGGL(gatew_kernel, dim3(64),       dim3(256), 0, stream, gate_A, gate_S, Wg);
    hipLaunchKernelGGL(phm_build,    dim3(8, 8),     dim3(256), 0, stream, attn_A, attn_S, WtAttn, 4, 256, 512);
    hipLaunchKernelGGL(phm_build,    dim3(250, 16),  dim3(256), 0, stream, lm_A, lm_S, WtLm, 2, 512, 16000);
    hipLaunchKernelGGL((gemm256<0>), dim3(128),      dim3(512), 0, stream,
                       xn, WtAttn, attn_b, (void*)qkbuf, 2048, 1024);
    hipLaunchKernelGGL(gate_kernel,  dim3(4096),     dim3(256), 0, stream, xn, Wg, gate_b, Gp);
    hipLaunchKernelGGL(scores_kernel,dim3(64, 8),    dim3(512), 0, stream, qkbuf, Gp, lens, out_trans);
    hipLaunchKernelGGL((gemm256<1>), dim3(2000),     dim3(512), 0, stream,
                       xn, WtLm, lm_b, (void*)out_vocab, 32000, 1024);
    hipLaunchKernelGGL(vocab_softmax_bf16, dim3(4096), dim3(256), 0, stream, out_vocab);
}